// Round 5
// baseline (53969.092 us; speedup 1.0000x reference)
//
#include <hip/hip_runtime.h>
#include <hip/hip_bf16.h>
#include <hip/hip_cooperative_groups.h>

namespace cg = cooperative_groups;

typedef unsigned short ushort_t;
typedef short s8v __attribute__((ext_vector_type(8)));
typedef float f4v __attribute__((ext_vector_type(4)));

#define TT   200
#define TMEL 400
#define OUTD 80

#define MFMA __builtin_amdgcn_mfma_f32_16x16x32_bf16

struct Params {
  const int* text;
  const void* raw[18];   // float inputs d_in[1..18]
  void* out;
  ushort_t* cv[18];      // canonical bf16 copies
  unsigned int* zbase;
  int zwords;
  ushort_t* enc_out;     // [b*200+s][512]
  ushort_t* proj;        // [b*200+s][1024]
  float* hp;             // [32][1024]
  float* exps;           // [2][6400]
  float* Z;              // [2][32]
  float* ctxhat;         // [2][16384]
  float* c_f; float* c_b; float* c_dec;
  ushort_t* h_f; ushort_t* h_b;   // [2][32*256]
  ushort_t* h_dec;                // [2][32*1024]
};

__device__ __forceinline__ float bf2f(ushort_t u) {
  union { unsigned int i; float f; } c; c.i = ((unsigned int)u) << 16; return c.f;
}
__device__ __forceinline__ ushort_t f2bf(float f) {
  union { float f; unsigned int i; } c; c.f = f;
  unsigned int i = c.i;
  unsigned int r = i + 0x7FFFu + ((i >> 16) & 1u);
  return (ushort_t)(r >> 16);
}
__device__ __forceinline__ float sigm(float x) {
  float e = __builtin_amdgcn_exp2f(-1.44269504f * x);
  return __builtin_amdgcn_rcpf(1.0f + e);
}
__device__ __forceinline__ float tanh_(float x) {
  float e = __builtin_amdgcn_exp2f(2.88539009f * x);
  return 1.0f - 2.0f * __builtin_amdgcn_rcpf(e + 1.0f);
}
__device__ __forceinline__ void store_out(void* out, int mode, long idx, float v) {
  if (mode) ((float*)out)[idx] = v;
  else      ((ushort_t*)out)[idx] = f2bf(v);
}

__global__ void __launch_bounds__(256, 1) k_mega(Params p) {
  cg::grid_group grid = cg::this_grid();
  __shared__ __align__(16) char sm[33 * 1024];
  const int tid = threadIdx.x, bid = blockIdx.x;
  const int lane = tid & 63, wv = tid >> 6, q = lane >> 4, l15 = lane & 15;
  const s8v zero8 = {0, 0, 0, 0, 0, 0, 0, 0};

  // ---- dtype mode detect (identical verdict in every block) ----
  int mode;
  {
    int* cnt = (int*)sm;
    const ushort_t* raw1 = (const ushort_t*)p.raw[1];  // emb
    int c = 0;
    for (int j = 0; j < 8; ++j) {
      int e = (raw1[(tid * 8 + j) * 2] >> 7) & 0xFF;
      c += (e >= 130);
    }
    cnt[tid] = c;
    __syncthreads();
    if (tid == 0) {
      int s = 0;
      for (int i = 0; i < 256; ++i) s += cnt[i];
      cnt[256] = (s > 64) ? 1 : 0;
    }
    __syncthreads();
    mode = cnt[256];
    __syncthreads();
  }

  // ---- INIT: zero state + convert all float inputs to bf16 ----
  {
    int gid = bid * 256 + tid;
    for (int i = gid; i < p.zwords; i += 65536) p.zbase[i] = 0u;
    const int sz[18] = {1024000, 37888, 262144, 262144, 1024, 262144, 262144, 1024,
                        1572864, 1024, 1024, 2424832, 4194304, 4096, 81920, 80, 1024, 1};
#pragma unroll
    for (int tn = 0; tn < 18; ++tn) {
      int n = sz[tn];
      ushort_t* dst = p.cv[tn];
      if (mode) {
        const float* s = (const float*)p.raw[tn];
        for (int i = gid; i < n; i += 65536) dst[i] = f2bf(s[i]);
      } else {
        const ushort_t* s = (const ushort_t*)p.raw[tn];
        for (int i = gid; i < n; i += 65536) dst[i] = s[i];
      }
    }
  }
  grid.sync();

  // ---- ENCODER: 200 steps, blocks 0..63 = (dir, mt, cg), 4 waves = K-quarters ----
  for (int t = 0; t < 200; ++t) {
    if (bid < 64) {
      int dir = bid >> 5, mt = (bid >> 4) & 1, cgx = bid & 15;
      const ushort_t* Wih = dir ? p.cv[5] : p.cv[2];
      const ushort_t* Whh = dir ? p.cv[6] : p.cv[3];
      const ushort_t* bi  = dir ? p.cv[7] : p.cv[4];
      float* cbuf = dir ? p.c_b : p.c_f;
      ushort_t* hbase = dir ? p.h_b : p.h_f;
      int tb = dir ? (199 - t) : t;
      const ushort_t* hR = hbase + (t & 1) * 8192;
      ushort_t* hW = hbase + ((t + 1) & 1) * 8192;
      int m = mt * 16 + l15;
      const ushort_t* xrow = p.cv[1] + (long)p.text[m * TT + tb] * 256;
      f4v acc[4];
#pragma unroll
      for (int s = 0; s < 4; ++s) acc[s] = (f4v){0.f, 0.f, 0.f, 0.f};
#pragma unroll
      for (int kk = 0; kk < 4; ++kk) {
        int kc = wv * 4 + kk;
        int k8 = kc * 32 + q * 8;
        s8v a = (k8 < 256) ? *(const s8v*)(xrow + k8)
                           : *(const s8v*)(hR + m * 256 + (k8 - 256));
#pragma unroll
        for (int s = 0; s < 4; ++s) {
          int n = s * 256 + cgx * 16 + l15;
          s8v bb = (k8 < 256) ? *(const s8v*)(Wih + (long)n * 256 + k8)
                              : *(const s8v*)(Whh + (long)n * 256 + (k8 - 256));
          acc[s] = MFMA(a, bb, acc[s], 0, 0, 0);
        }
      }
      f4v* red = (f4v*)sm;
#pragma unroll
      for (int s = 0; s < 4; ++s) red[(wv * 4 + s) * 64 + lane] = acc[s];
      __syncthreads();
      if (wv == 0) {
        int jcol = cgx * 16 + l15;
#pragma unroll
        for (int s = 0; s < 4; ++s) {
          f4v g4 = red[s * 64 + lane] + red[(4 + s) * 64 + lane] +
                   red[(8 + s) * 64 + lane] + red[(12 + s) * 64 + lane];
          float bias = bf2f(bi[s * 256 + jcol]);
          acc[s] = g4 + (f4v){bias, bias, bias, bias};
        }
#pragma unroll
        for (int r = 0; r < 4; ++r) {
          int mr = mt * 16 + q * 4 + r;
          int ci = mr * 256 + jcol;
          float cold = cbuf[ci];
          float cn = sigm(acc[1][r]) * cold + sigm(acc[0][r]) * tanh_(acc[2][r]);
          float hn = sigm(acc[3][r]) * tanh_(cn);
          cbuf[ci] = cn;
          ushort_t hb = f2bf(hn);
          hW[ci] = hb;
          p.enc_out[((long)mr * TT + tb) * 512 + dir * 256 + jcol] = hb;
        }
      }
    }
    grid.sync();
  }

  // ---- PROJ: enc_out @ Ws_enc^T + bs -> proj (bf16) ----
  {
    for (int i = 0; i < 25; ++i) {
      int jj = (bid * 4 + wv) * 25 + i;        // 25600 jobs
      int mtj = jj >> 6, nt = jj & 63;
      int mm = mtj * 16 + l15;
      const ushort_t* arow = p.enc_out + (long)mm * 512;
      int n = nt * 16 + l15;
      const ushort_t* brow = p.cv[8] + (long)n * 1536;
      f4v acc = {0.f, 0.f, 0.f, 0.f};
#pragma unroll
      for (int kc = 0; kc < 16; ++kc) {
        s8v a = *(const s8v*)(arow + kc * 32 + q * 8);
        s8v bb = *(const s8v*)(brow + kc * 32 + q * 8);
        acc = MFMA(a, bb, acc, 0, 0, 0);
      }
      float bias = bf2f(p.cv[9][n]);
#pragma unroll
      for (int r = 0; r < 4; ++r)
        p.proj[(long)(mtj * 16 + q * 4 + r) * 1024 + n] = f2bf(acc[r] + bias);
    }
  }
  grid.sync();

  // ---- DECODER: 400 steps x 3 syncs ----
  for (int t = 0; t <= 400; ++t) {
    int pp = t & 1;
    const ushort_t* hR = p.h_dec + pp * 32768;

    // ======== S1: hp GEMM, mel/stop(t-1), aligns(t-1) ========
    if (bid < 64) {
      if (t < 400) {                       // hp = h @ Ws_dec^T
        int mtj = bid >> 5, ntp = bid & 31;
        int nt = ntp * 2 + (wv >> 1);
        int kh = wv & 1;
        int mm = mtj * 16 + l15;
        int n = nt * 16 + l15;
        const ushort_t* brow = p.cv[8] + (long)n * 1536 + 512;
        f4v acc = {0.f, 0.f, 0.f, 0.f};
#pragma unroll
        for (int kc = 0; kc < 16; ++kc) {
          int k8 = kh * 512 + kc * 32 + q * 8;
          s8v a = *(const s8v*)(hR + mm * 1024 + k8);
          s8v bb = *(const s8v*)(brow + k8);
          acc = MFMA(a, bb, acc, 0, 0, 0);
        }
        f4v* red = (f4v*)sm;
        red[wv * 64 + lane] = acc;
        __syncthreads();
        if ((wv & 1) == 0) {
          f4v s4 = red[wv * 64 + lane] + red[(wv + 1) * 64 + lane];
#pragma unroll
          for (int r = 0; r < 4; ++r)
            p.hp[(mtj * 16 + q * 4 + r) * 1024 + nt * 16 + l15] = s4[r];
        }
      }
    } else if (bid < 74) {                 // mel output for step t-1
      if (t > 0) {
        int jid = bid - 64;
        int mtj = jid / 5, nt = jid % 5;
        int mm = mtj * 16 + l15;
        int n = nt * 16 + l15;
        const ushort_t* brow = p.cv[14] + (long)n * 1024;
        f4v acc = {0.f, 0.f, 0.f, 0.f};
#pragma unroll
        for (int kc = 0; kc < 8; ++kc) {
          int k8 = wv * 256 + kc * 32 + q * 8;
          s8v a = *(const s8v*)(hR + mm * 1024 + k8);
          s8v bb = *(const s8v*)(brow + k8);
          acc = MFMA(a, bb, acc, 0, 0, 0);
        }
        f4v* red = (f4v*)sm;
        red[wv * 64 + lane] = acc;
        __syncthreads();
        if (wv == 0) {
          f4v s4 = red[lane] + red[64 + lane] + red[128 + lane] + red[192 + lane];
          float bias = bf2f(p.cv[15][n]);
#pragma unroll
          for (int r = 0; r < 4; ++r)
            store_out(p.out, mode,
                      ((long)(mtj * 16 + q * 4 + r) * TMEL + (t - 1)) * OUTD + n,
                      s4[r] + bias);
        }
      }
    } else if (bid == 74) {                // stop output for step t-1
      if (t > 0) {
        int b = tid >> 3, kp = tid & 7;
        const ushort_t* Wst = p.cv[16];
        float s = 0.f;
        for (int k = kp * 128; k < kp * 128 + 128; ++k)
          s += bf2f(hR[b * 1024 + k]) * bf2f(Wst[k]);
        s += __shfl_xor(s, 1, 64);
        s += __shfl_xor(s, 2, 64);
        s += __shfl_xor(s, 4, 64);
        if (kp == 0)
          store_out(p.out, mode, 1024000 + b * TMEL + (t - 1),
                    sigm(s + bf2f(p.cv[17][0])));
      }
    } else if (bid < 100) {                // aligns output for step t-1
      if (t > 0) {
        int idx = (bid - 75) * 256 + tid;  // 0..6399
        int b = idx / 200, s = idx - b * 200;
        int p1 = (t - 1) & 1;
        float val = p.exps[p1 * 6400 + b * 200 + s] *
                    __builtin_amdgcn_rcpf(p.Z[p1 * 32 + b]);
        store_out(p.out, mode, 1036800 + ((long)b * TMEL + (t - 1)) * TT + s, val);
      }
    }
    if (t == 400) break;
    grid.sync();

    // ======== S2: energies -> exp -> Z/ctx partials; zero other parity ========
    {
      int b = bid >> 3, s0 = (bid & 7) * 25;
      float* exl = (float*)sm;
      const ushort_t* vvp = p.cv[10];
      for (int si = wv; si < 25; si += 4) {
        int s = s0 + si;
        const ushort_t* prow = p.proj + (long)(b * 200 + s) * 1024;
        float part = 0.f;
#pragma unroll
        for (int it = 0; it < 16; ++it) {
          int d = lane + it * 64;
          float x = bf2f(prow[d]) + p.hp[b * 1024 + d];
          part += tanh_(x) * bf2f(vvp[d]);
        }
#pragma unroll
        for (int off = 32; off >= 1; off >>= 1) part += __shfl_xor(part, off, 64);
        if (lane == 0) {
          float e = __builtin_amdgcn_exp2f(1.44269504f * part);
          exl[si] = e;
          p.exps[pp * 6400 + b * 200 + s] = e;
        }
      }
      __syncthreads();
      if (tid == 0) {
        float ss = 0.f;
        for (int i = 0; i < 25; ++i) ss += exl[i];
        atomicAdd(&p.Z[pp * 32 + b], ss);
      }
      int e0 = tid * 2;
      float a0 = 0.f, a1 = 0.f;
      for (int i = 0; i < 25; ++i) {
        float wgt = exl[i];
        const ushort_t* er = p.enc_out + (long)(b * 200 + s0 + i) * 512 + e0;
        a0 += wgt * bf2f(er[0]);
        a1 += wgt * bf2f(er[1]);
      }
      atomicAdd(&p.ctxhat[pp * 16384 + b * 512 + e0], a0);
      atomicAdd(&p.ctxhat[pp * 16384 + b * 512 + e0 + 1], a1);
      int zi = bid * 256 + tid;
      if (zi < 16384) p.ctxhat[(pp ^ 1) * 16384 + zi] = 0.f;
      else if (zi < 16416) p.Z[(pp ^ 1) * 32 + (zi - 16384)] = 0.f;
    }
    grid.sync();

    // ======== S3: gates GEMM (K=1632, 4-way K-split) + LSTM cell ========
    if (bid < 128) {
      int mtj = bid >> 6, cgj = bid & 63;
      ushort_t* lctx = (ushort_t*)sm;          // 16 KB
      f4v* red = (f4v*)(sm + 16384);           // 16 KB
      for (int i = tid; i < 8192; i += 256) {
        int row = i >> 9, e = i & 511;
        int b = mtj * 16 + row;
        lctx[i] = f2bf(p.ctxhat[pp * 16384 + b * 512 + e] *
                       __builtin_amdgcn_rcpf(p.Z[pp * 32 + b]));
      }
      __syncthreads();
      int kc0 = (wv * 51) >> 2, kc1 = ((wv + 1) * 51) >> 2;
      f4v acc[4];
#pragma unroll
      for (int s = 0; s < 4; ++s) acc[s] = (f4v){0.f, 0.f, 0.f, 0.f};
      int mm = mtj * 16 + l15;
      for (int kc = kc0; kc < kc1; ++kc) {
        int k8 = kc * 32 + q * 8;
        s8v a;
        if (k8 < 80)
          a = (t == 0) ? zero8
                       : *(const s8v*)(p.cv[0] + ((long)mm * TMEL + (t - 1)) * OUTD + k8);
        else if (k8 < 592)  a = *(const s8v*)(lctx + l15 * 512 + (k8 - 80));
        else if (k8 < 1616) a = *(const s8v*)(hR + mm * 1024 + (k8 - 592));
        else                a = zero8;
#pragma unroll
        for (int s = 0; s < 4; ++s) {
          int n = s * 1024 + cgj * 16 + l15;
          s8v bb;
          if (k8 < 592)       bb = *(const s8v*)(p.cv[11] + (long)n * 592 + k8);
          else if (k8 < 1616) bb = *(const s8v*)(p.cv[12] + (long)n * 1024 + (k8 - 592));
          else                bb = zero8;
          acc[s] = MFMA(a, bb, acc[s], 0, 0, 0);
        }
      }
#pragma unroll
      for (int s = 0; s < 4; ++s) red[(wv * 4 + s) * 64 + lane] = acc[s];
      __syncthreads();
      if (wv == 0) {
        int jcol = cgj * 16 + l15;
        ushort_t* hW = p.h_dec + ((t + 1) & 1) * 32768;
        f4v gs[4];
#pragma unroll
        for (int s = 0; s < 4; ++s) {
          gs[s] = red[s * 64 + lane] + red[(4 + s) * 64 + lane] +
                  red[(8 + s) * 64 + lane] + red[(12 + s) * 64 + lane];
          float bias = bf2f(p.cv[13][s * 1024 + jcol]);
          gs[s] = gs[s] + (f4v){bias, bias, bias, bias};
        }
#pragma unroll
        for (int r = 0; r < 4; ++r) {
          int mr = mtj * 16 + q * 4 + r;
          int ci = mr * 1024 + jcol;
          float cold = p.c_dec[ci];
          float cn = sigm(gs[1][r]) * cold + sigm(gs[0][r]) * tanh_(gs[2][r]);
          float hn = sigm(gs[3][r]) * tanh_(cn);
          p.c_dec[ci] = cn;
          hW[ci] = f2bf(hn);
        }
      }
    }
    grid.sync();
  }
}

extern "C" void kernel_launch(void* const* d_in, const int* in_sizes, int n_in,
                              void* d_out, int out_size, void* d_ws, size_t ws_size,
                              hipStream_t stream) {
  Params pa;
  pa.text = (const int*)d_in[0];
  for (int i = 0; i < 18; ++i) pa.raw[i] = d_in[i + 1];
  pa.out = d_out;

  char* p = (char*)d_ws;
  auto carve = [&](size_t bytes) -> char* {
    char* r = p;
    p += (bytes + 255) & ~(size_t)255;
    return r;
  };
  // --- zeroed state region (contiguous) ---
  char* zbase = p;
  pa.c_f    = (float*)carve(8192 * 4);
  pa.c_b    = (float*)carve(8192 * 4);
  pa.c_dec  = (float*)carve(32768 * 4);
  pa.h_f    = (ushort_t*)carve(16384 * 2);
  pa.h_b    = (ushort_t*)carve(16384 * 2);
  pa.h_dec  = (ushort_t*)carve(65536 * 2);
  pa.ctxhat = (float*)carve(32768 * 4);
  pa.Z      = (float*)carve(64 * 4);
  pa.zbase  = (unsigned int*)zbase;
  pa.zwords = (int)((p - zbase) / 4);
  // --- canonical bf16 inputs ---
  static const int cvn[18] = {
      1024000, 37888, 262144, 262144, 1024, 262144, 262144, 1024,
      1572864, 1024, 1024, 2424832, 4194304, 4096, 81920, 80, 1024, 1};
  for (int i = 0; i < 18; ++i) pa.cv[i] = (ushort_t*)carve((size_t)cvn[i] * 2);
  // --- runtime buffers ---
  pa.enc_out = (ushort_t*)carve(3276800ull * 2);
  pa.proj    = (ushort_t*)carve(6553600ull * 2);
  pa.hp      = (float*)carve(32768 * 4);
  pa.exps    = (float*)carve(12800 * 4);

  void* kp[] = {(void*)&pa};
  hipLaunchCooperativeKernel((const void*)k_mega, dim3(256), dim3(256), kp, 0, stream);
}